// Round 8
// baseline (9264.423 us; speedup 1.0000x reference)
//
#include <hip/hip_runtime.h>
#include <math.h>

// Problem constants (Elman RNN)
#define TT 4096
#define HH 2048
#define OO 512

#define NB  128   // scan blocks (128 CUs active)
#define RPB 16    // rows per block = HH/NB

// ---------------------------------------------------------------------------
// Phase 1 & 3: fp32 NT GEMM  C[m,n] = sum_k A[m,k]*B[n,k] + bias[n]
// 128x128 tile, 256 threads, 8x8 per thread, BK=8. (unchanged)
// ---------------------------------------------------------------------------
__global__ __launch_bounds__(256) void gemm_nt_bias(
    const float* __restrict__ A, const float* __restrict__ B,
    const float* __restrict__ bias, float* __restrict__ C,
    int M, int N, int K)
{
    __shared__ float As[8][128];
    __shared__ float Bs[8][128];

    const int tid = threadIdx.x;
    const int bm = blockIdx.x * 128;
    const int bn = blockIdx.y * 128;

    const int lrow = tid >> 1;
    const int lk   = (tid & 1) * 4;

    const int ty = tid >> 4;
    const int tx = tid & 15;

    float acc[8][8];
#pragma unroll
    for (int i = 0; i < 8; i++)
#pragma unroll
        for (int j = 0; j < 8; j++) acc[i][j] = 0.f;

    for (int k0 = 0; k0 < K; k0 += 8) {
        float4 av = *(const float4*)&A[(size_t)(bm + lrow) * K + k0 + lk];
        float4 bv = *(const float4*)&B[(size_t)(bn + lrow) * K + k0 + lk];
        __syncthreads();
        As[lk + 0][lrow] = av.x; As[lk + 1][lrow] = av.y;
        As[lk + 2][lrow] = av.z; As[lk + 3][lrow] = av.w;
        Bs[lk + 0][lrow] = bv.x; Bs[lk + 1][lrow] = bv.y;
        Bs[lk + 2][lrow] = bv.z; Bs[lk + 3][lrow] = bv.w;
        __syncthreads();
#pragma unroll
        for (int kk = 0; kk < 8; kk++) {
            float a[8], b[8];
            *(float4*)&a[0] = *(const float4*)&As[kk][ty * 4];
            *(float4*)&a[4] = *(const float4*)&As[kk][64 + ty * 4];
            *(float4*)&b[0] = *(const float4*)&Bs[kk][tx * 4];
            *(float4*)&b[4] = *(const float4*)&Bs[kk][64 + tx * 4];
#pragma unroll
            for (int i = 0; i < 8; i++)
#pragma unroll
                for (int j = 0; j < 8; j++)
                    acc[i][j] += a[i] * b[j];
        }
    }

#pragma unroll
    for (int g = 0; g < 2; g++) {
        const int n = bn + g * 64 + tx * 4;
        float4 bv = *(const float4*)&bias[n];
#pragma unroll
        for (int i = 0; i < 8; i++) {
            const int m = bm + ((i < 4) ? (ty * 4 + i) : (64 + ty * 4 + (i - 4)));
            float4 cv;
            cv.x = acc[i][g * 4 + 0] + bv.x;
            cv.y = acc[i][g * 4 + 1] + bv.y;
            cv.z = acc[i][g * 4 + 2] + bv.z;
            cv.w = acc[i][g * 4 + 3] + bv.w;
            *(float4*)&C[(size_t)m * N + n] = cv;
        }
    }
}

// ---------------------------------------------------------------------------
// Phase 2: persistent scan, 128 blocks x 1024 threads, block owns 16 rows.
//
// R8 (vs R7, same validated topology):
//  (1) bank fix: subchunk map q*32 -> interleaved jj*16 + q*4, so the 4
//      distinct float4s per ds_read_b128 hit disjoint bank groups
//      (R7's q*128B stride aliased all 4 groups onto the same 4 banks:
//      3.35e7 conflicts).
//  (2) pipelined 2-deep poll: issue next pair before checking previous
//      (s_waitcnt vmcnt(2)) -> discovery quantization ~RT/2 -> ~RT/4.
//  (3) publisher tail: branch-free tanh = (e-1)*rcp(e+1), e=exp2(2z*log2e),
//      z clamped +-15; mailbox publish store issued BEFORE outs store.
// ---------------------------------------------------------------------------
__global__ __launch_bounds__(1024, 4) void rnn_scan(
    const float* __restrict__ xp,    // (T,H) input projection incl. b_ih
    const float* __restrict__ Whh,   // (H,H)
    const float* __restrict__ bhh,   // (H)
    const float* __restrict__ h0,    // (H)
    float* __restrict__ outs,        // (T,H) hidden states out
    unsigned long long* __restrict__ mbox)  // [2][HH] tagged-h mailbox
{
    const int b    = blockIdx.x;     // 0..127
    const int tid  = threadIdx.x;    // 0..1023
    const int wave = tid >> 6;       // 0..15
    const int lane = tid & 63;
    const int r    = lane & 15;      // local row 0..15
    const int q    = lane >> 4;      // 0..3: interleaved 4-float subchunk
    const int row  = b * RPB + r;    // global row this thread accumulates
    const int m0   = wave * 128 + 2 * lane; // my 2 mailbox words

    // weights pinned (atomic loads can't be rematerialized into the loop)
    // w[jj*4+i] pairs with h[wave*128 + jj*16 + q*4 + i]
    float w[32];
#pragma unroll
    for (int jj = 0; jj < 8; ++jj)
#pragma unroll
        for (int i = 0; i < 4; ++i)
            w[jj * 4 + i] = __hip_atomic_load(
                &Whh[(size_t)row * HH + wave * 128 + jj * 16 + q * 4 + i],
                __ATOMIC_RELAXED, __HIP_MEMORY_SCOPE_WORKGROUP);

    const bool is_writer = (wave == 0) && (lane < RPB);
    const float bias = is_writer ? bhh[b * RPB + lane] : 0.f;

    __shared__ float hs[HH];               // staged h, wave-private chunks
    __shared__ float partial[16][68];      // [k-chunk wave][q*17 + r]

    for (int t = 0; t < TT; ++t) {
        // xp load: independent of h, issue before the poll
        float xpv = is_writer ? xp[(size_t)t * HH + b * RPB + lane] : 0.f;

        // stage MY wave's 128-float chunk (2 words/lane), wave-private
        if (t == 0) {
            float2 hv; hv.x = h0[m0]; hv.y = h0[m0 + 1];
            *(float2*)&hs[m0] = hv;
        } else {
            const unsigned int want = (unsigned int)t;
            const unsigned long long* mb = mbox + (size_t)(t & 1) * HH;
            // 2-deep pipelined poll: next pair in flight while checking prev
            unsigned long long v0 = __hip_atomic_load(&mb[m0],
                __ATOMIC_RELAXED, __HIP_MEMORY_SCOPE_AGENT);
            unsigned long long v1 = __hip_atomic_load(&mb[m0 + 1],
                __ATOMIC_RELAXED, __HIP_MEMORY_SCOPE_AGENT);
            for (;;) {
                unsigned long long u0 = __hip_atomic_load(&mb[m0],
                    __ATOMIC_RELAXED, __HIP_MEMORY_SCOPE_AGENT);
                unsigned long long u1 = __hip_atomic_load(&mb[m0 + 1],
                    __ATOMIC_RELAXED, __HIP_MEMORY_SCOPE_AGENT);
                if ((((unsigned int)(v0 >> 32)) == want) &
                    (((unsigned int)(v1 >> 32)) == want)) break;
                v0 = u0; v1 = u1;
            }
            float2 hv;
            hv.x = __uint_as_float((unsigned int)v0);
            hv.y = __uint_as_float((unsigned int)v1);
            *(float2*)&hs[m0] = hv;   // same-wave write->read: lgkmcnt only
        }

        // matvec partial: 8 conflict-free broadcast ds_read_b128 + 32 FMA
        const float* hk = &hs[wave * 128 + q * 4];
        float p = 0.f;
#pragma unroll
        for (int jj = 0; jj < 8; ++jj) {
            float4 h4 = *(const float4*)&hk[jj * 16];
            p += w[jj * 4 + 0] * h4.x + w[jj * 4 + 1] * h4.y
               + w[jj * 4 + 2] * h4.z + w[jj * 4 + 3] * h4.w;
        }
        partial[wave][q * 17 + r] = p;
        __syncthreads();   // (B) the ONLY barrier per step

        if (wave == 0) {
            // lane l: row = l&15, qq = l>>4; sum over the 16 k-chunk waves
            const int idx = (lane >> 4) * 17 + (lane & 15);
            float s = 0.f;
#pragma unroll
            for (int g = 0; g < 16; ++g) s += partial[g][idx];
            s += __shfl_xor(s, 16, 64);   // fold qq bit 0
            s += __shfl_xor(s, 32, 64);   // fold qq bit 1
            if (lane < RPB) {
                // branch-free tanh: (e-1)/(e+1), e = e^(2z)
                float z = xpv + bias + s;
                z = fminf(15.f, fmaxf(-15.f, z));
                float e = __builtin_exp2f(z * 2.885390082f);
                float hv = (e - 1.f) * __builtin_amdgcn_rcpf(e + 1.f);
                unsigned long long pk =
                    ((unsigned long long)(unsigned int)(t + 1) << 32) |
                    (unsigned long long)__float_as_uint(hv);
                // critical store first: single-instruction 128B publish
                __hip_atomic_store(&mbox[(size_t)((t + 1) & 1) * HH + b * RPB + lane],
                                   pk, __ATOMIC_RELAXED, __HIP_MEMORY_SCOPE_AGENT);
                outs[(size_t)t * HH + b * RPB + lane] = hv;  // plain cached
            }
        }
        // no other barrier: partial[w] overwrite for t+1 is gated by wave w's
        // t+1 poll, which requires this block's wave-0 publish (after reads).
    }
}

// ---------------------------------------------------------------------------
extern "C" void kernel_launch(void* const* d_in, const int* in_sizes, int n_in,
                              void* d_out, int out_size, void* d_ws, size_t ws_size,
                              hipStream_t stream)
{
    const float* x     = (const float*)d_in[0];  // (T,1,H)
    const float* W_ih  = (const float*)d_in[1];  // (H,H)
    const float* W_hh  = (const float*)d_in[2];  // (H,H)
    const float* b_ih  = (const float*)d_in[3];  // (H)
    const float* b_hh  = (const float*)d_in[4];  // (H)
    const float* W_lin = (const float*)d_in[5];  // (O,H)
    const float* b_lin = (const float*)d_in[6];  // (O)
    const float* h0    = (const float*)d_in[7];  // (1,1,H)
    float* out = (float*)d_out;                  // (T,1,O)

    char* ws = (char*)d_ws;
    float* xp    = (float*)ws;                                       // 32 MB
    float* outs  = (float*)(ws + (size_t)TT * HH * 4);               // 32 MB
    unsigned long long* mbox =
        (unsigned long long*)(ws + 2 * (size_t)TT * HH * 4);         // 32 KB

    // no mailbox init needed: t==0 reads h0 directly; poisoned tag
    // 0xAAAAAAAA never equals a wanted tag (t < 4096).

    // Phase 1: xp = x @ W_ih^T + b_ih
    gemm_nt_bias<<<dim3(TT / 128, HH / 128), 256, 0, stream>>>(
        x, W_ih, b_ih, xp, TT, HH, HH);

    // Phase 2: sequential scan (persistent, 128 co-resident blocks)
    rnn_scan<<<NB, 1024, 0, stream>>>(xp, W_hh, b_hh, h0, outs, mbox);

    // Phase 3: out = outs @ W_lin^T + b_lin
    gemm_nt_bias<<<dim3(TT / 128, OO / 128), 256, 0, stream>>>(
        outs, W_lin, b_lin, out, TT, OO, HH);
}

// Round 9
// 7674.609 us; speedup vs baseline: 1.2072x; 1.2072x over previous
//
#include <hip/hip_runtime.h>
#include <math.h>

// Problem constants (Elman RNN)
#define TT 4096
#define HH 2048
#define OO 512

#define NB  128   // scan blocks (128 CUs active)
#define RPB 16    // rows per block = HH/NB
#define MBW (HH/2) // mailbox words per buffer (fp16 x2 per word)

typedef __fp16 half2v __attribute__((ext_vector_type(2)));

// ---------------------------------------------------------------------------
// Phase 1 & 3: fp32 NT GEMM  C[m,n] = sum_k A[m,k]*B[n,k] + bias[n]
// 128x128 tile, 256 threads, 8x8 per thread, BK=8. (unchanged)
// ---------------------------------------------------------------------------
__global__ __launch_bounds__(256) void gemm_nt_bias(
    const float* __restrict__ A, const float* __restrict__ B,
    const float* __restrict__ bias, float* __restrict__ C,
    int M, int N, int K)
{
    __shared__ float As[8][128];
    __shared__ float Bs[8][128];

    const int tid = threadIdx.x;
    const int bm = blockIdx.x * 128;
    const int bn = blockIdx.y * 128;

    const int lrow = tid >> 1;
    const int lk   = (tid & 1) * 4;

    const int ty = tid >> 4;
    const int tx = tid & 15;

    float acc[8][8];
#pragma unroll
    for (int i = 0; i < 8; i++)
#pragma unroll
        for (int j = 0; j < 8; j++) acc[i][j] = 0.f;

    for (int k0 = 0; k0 < K; k0 += 8) {
        float4 av = *(const float4*)&A[(size_t)(bm + lrow) * K + k0 + lk];
        float4 bv = *(const float4*)&B[(size_t)(bn + lrow) * K + k0 + lk];
        __syncthreads();
        As[lk + 0][lrow] = av.x; As[lk + 1][lrow] = av.y;
        As[lk + 2][lrow] = av.z; As[lk + 3][lrow] = av.w;
        Bs[lk + 0][lrow] = bv.x; Bs[lk + 1][lrow] = bv.y;
        Bs[lk + 2][lrow] = bv.z; Bs[lk + 3][lrow] = bv.w;
        __syncthreads();
#pragma unroll
        for (int kk = 0; kk < 8; kk++) {
            float a[8], b[8];
            *(float4*)&a[0] = *(const float4*)&As[kk][ty * 4];
            *(float4*)&a[4] = *(const float4*)&As[kk][64 + ty * 4];
            *(float4*)&b[0] = *(const float4*)&Bs[kk][tx * 4];
            *(float4*)&b[4] = *(const float4*)&Bs[kk][64 + tx * 4];
#pragma unroll
            for (int i = 0; i < 8; i++)
#pragma unroll
                for (int j = 0; j < 8; j++)
                    acc[i][j] += a[i] * b[j];
        }
    }

#pragma unroll
    for (int g = 0; g < 2; g++) {
        const int n = bn + g * 64 + tx * 4;
        float4 bv = *(const float4*)&bias[n];
#pragma unroll
        for (int i = 0; i < 8; i++) {
            const int m = bm + ((i < 4) ? (ty * 4 + i) : (64 + ty * 4 + (i - 4)));
            float4 cv;
            cv.x = acc[i][g * 4 + 0] + bv.x;
            cv.y = acc[i][g * 4 + 1] + bv.y;
            cv.z = acc[i][g * 4 + 2] + bv.z;
            cv.w = acc[i][g * 4 + 3] + bv.w;
            *(float4*)&C[(size_t)m * N + n] = cv;
        }
    }
}

// ---------------------------------------------------------------------------
// Phase 2: persistent scan, 128 blocks x 1024 threads, block owns 16 rows.
//
// R9 (vs R8):
//  (1) REVERT the 2-deep poll (it checked stale data -> +1 RT/step lag bug;
//      R8 regressed +0.25us/step). Back to the validated simple do-while.
//  (2) fp16-PACKED mailbox: word = tag32 | (fp16 h[2j+1] | fp16 h[2j]).
//      - consumer wave: ONE 8B load/lane covers its whole 128-row chunk
//        (512B, 8 lines -- half of R8's 1KB/16 lines of poll traffic)
//      - publisher: 16 rows -> ONE 64B line, one 8-lane store instruction
//        (single-line commit keeps the publish effectively atomic)
//      fp16 rel-err ~1e-3 touches only the recurrent path; outs[] keeps
//      exact fp32 for phase 3. (R8's identical-conflict counter proved the
//      matvec/banks were never the bottleneck; the exchange is.)
// ---------------------------------------------------------------------------
__global__ __launch_bounds__(1024, 4) void rnn_scan(
    const float* __restrict__ xp,    // (T,H) input projection incl. b_ih
    const float* __restrict__ Whh,   // (H,H)
    const float* __restrict__ bhh,   // (H)
    const float* __restrict__ h0,    // (H)
    float* __restrict__ outs,        // (T,H) hidden states out
    unsigned long long* __restrict__ mbox)  // [2][MBW] tagged fp16x2 mailbox
{
    const int b    = blockIdx.x;     // 0..127
    const int tid  = threadIdx.x;    // 0..1023
    const int wave = tid >> 6;       // 0..15
    const int lane = tid & 63;
    const int r    = lane & 15;      // local row 0..15
    const int q    = lane >> 4;      // 0..3: interleaved 4-float subchunk
    const int row  = b * RPB + r;    // global row this thread accumulates
    const int m0   = wave * 64 + lane;      // my mailbox word (covers 2 rows)
    const int s0   = wave * 128 + 2 * lane; // my 2 floats in hs

    // weights pinned (atomic loads can't be rematerialized into the loop)
    // w[jj*4+i] pairs with h[wave*128 + jj*16 + q*4 + i]
    float w[32];
#pragma unroll
    for (int jj = 0; jj < 8; ++jj)
#pragma unroll
        for (int i = 0; i < 4; ++i)
            w[jj * 4 + i] = __hip_atomic_load(
                &Whh[(size_t)row * HH + wave * 128 + jj * 16 + q * 4 + i],
                __ATOMIC_RELAXED, __HIP_MEMORY_SCOPE_WORKGROUP);

    const bool is_writer = (wave == 0) && (lane < RPB);
    const float bias = is_writer ? bhh[b * RPB + lane] : 0.f;

    __shared__ float hs[HH];               // staged h (fp32), wave-private
    __shared__ float partial[16][68];      // [k-chunk wave][q*17 + r]

    for (int t = 0; t < TT; ++t) {
        // xp load: independent of h, issue before the poll
        float xpv = is_writer ? xp[(size_t)t * HH + b * RPB + lane] : 0.f;

        // stage MY wave's 128-float chunk: ONE tagged word per lane
        if (t == 0) {
            float2 hv; hv.x = h0[s0]; hv.y = h0[s0 + 1];
            *(float2*)&hs[s0] = hv;
        } else {
            const unsigned int want = (unsigned int)t;
            const unsigned long long* mb = mbox + (size_t)(t & 1) * MBW;
            unsigned long long v;
            do {
                v = __hip_atomic_load(&mb[m0],
                    __ATOMIC_RELAXED, __HIP_MEMORY_SCOPE_AGENT);
            } while ((unsigned int)(v >> 32) != want);
            half2v hp = __builtin_bit_cast(half2v, (unsigned int)v);
            float2 hv;
            hv.x = (float)hp[0];
            hv.y = (float)hp[1];
            *(float2*)&hs[s0] = hv;   // same-wave write->read: lgkmcnt only
        }

        // matvec partial: 8 broadcast ds_read_b128 + 32 FMA (interleaved map)
        const float* hk = &hs[wave * 128 + q * 4];
        float p = 0.f;
#pragma unroll
        for (int jj = 0; jj < 8; ++jj) {
            float4 h4 = *(const float4*)&hk[jj * 16];
            p += w[jj * 4 + 0] * h4.x + w[jj * 4 + 1] * h4.y
               + w[jj * 4 + 2] * h4.z + w[jj * 4 + 3] * h4.w;
        }
        partial[wave][q * 17 + r] = p;
        __syncthreads();   // (B) the ONLY barrier per step

        if (wave == 0) {
            // lane l: row = l&15, qq = l>>4; sum over the 16 k-chunk waves
            const int idx = (lane >> 4) * 17 + (lane & 15);
            float s = 0.f;
#pragma unroll
            for (int g = 0; g < 16; ++g) s += partial[g][idx];
            s += __shfl_xor(s, 16, 64);   // fold qq bit 0
            s += __shfl_xor(s, 32, 64);   // fold qq bit 1
            // every lane computes hv for row lane&15 (data valid lanes<16;
            // lanes>=16 compute finite garbage, masked below)
            float z = xpv + bias + s;
            z = fminf(15.f, fmaxf(-15.f, z));
            float e = __builtin_exp2f(z * 2.885390082f);
            float hv = (e - 1.f) * __builtin_amdgcn_rcpf(e + 1.f);
            // pack rows 2i,2i+1 into lane i (i<8): one 64B-line publish
            float ha = __shfl(hv, 2 * lane, 64);
            float hb = __shfl(hv, 2 * lane + 1, 64);
            if (lane < 8) {
                half2v pk2 = __builtin_amdgcn_cvt_pkrtz(ha, hb);
                unsigned int pb = __builtin_bit_cast(unsigned int, pk2);
                unsigned long long word =
                    ((unsigned long long)(unsigned int)(t + 1) << 32) |
                    (unsigned long long)pb;
                __hip_atomic_store(&mbox[(size_t)((t + 1) & 1) * MBW + b * 8 + lane],
                                   word, __ATOMIC_RELAXED, __HIP_MEMORY_SCOPE_AGENT);
            }
            if (lane < RPB)
                outs[(size_t)t * HH + b * RPB + lane] = hv;  // exact fp32
        }
        // no other barrier: partial[w] overwrite for t+1 is gated by wave w's
        // t+1 poll, which requires this block's wave-0 publish (after reads).
    }
}

// ---------------------------------------------------------------------------
extern "C" void kernel_launch(void* const* d_in, const int* in_sizes, int n_in,
                              void* d_out, int out_size, void* d_ws, size_t ws_size,
                              hipStream_t stream)
{
    const float* x     = (const float*)d_in[0];  // (T,1,H)
    const float* W_ih  = (const float*)d_in[1];  // (H,H)
    const float* W_hh  = (const float*)d_in[2];  // (H,H)
    const float* b_ih  = (const float*)d_in[3];  // (H)
    const float* b_hh  = (const float*)d_in[4];  // (H)
    const float* W_lin = (const float*)d_in[5];  // (O,H)
    const float* b_lin = (const float*)d_in[6];  // (O)
    const float* h0    = (const float*)d_in[7];  // (1,1,H)
    float* out = (float*)d_out;                  // (T,1,O)

    char* ws = (char*)d_ws;
    float* xp    = (float*)ws;                                       // 32 MB
    float* outs  = (float*)(ws + (size_t)TT * HH * 4);               // 32 MB
    unsigned long long* mbox =
        (unsigned long long*)(ws + 2 * (size_t)TT * HH * 4);         // 16 KB

    // no mailbox init needed: t==0 reads h0 directly; poisoned tag
    // 0xAAAAAAAA never equals a wanted tag (t < 4096).

    // Phase 1: xp = x @ W_ih^T + b_ih
    gemm_nt_bias<<<dim3(TT / 128, HH / 128), 256, 0, stream>>>(
        x, W_ih, b_ih, xp, TT, HH, HH);

    // Phase 2: sequential scan (persistent, 128 co-resident blocks)
    rnn_scan<<<NB, 1024, 0, stream>>>(xp, W_hh, b_hh, h0, outs, mbox);

    // Phase 3: out = outs @ W_lin^T + b_lin
    gemm_nt_bias<<<dim3(TT / 128, OO / 128), 256, 0, stream>>>(
        outs, W_lin, b_lin, out, TT, OO, HH);
}

// Round 10
// 7520.179 us; speedup vs baseline: 1.2319x; 1.0205x over previous
//
#include <hip/hip_runtime.h>
#include <math.h>

// Problem constants (Elman RNN)
#define TT 4096
#define HH 2048
#define OO 512

#define NB  128    // scan blocks
#define RPB 16     // rows per block = HH/NB
#define MBW (HH/2) // mailbox words per buffer (fp16 x2 per word)

#define CHUNK_T 64             // t-rows per xp chunk
#define NCHUNK  (TT/CHUNK_T)   // 64 chunks
#define HTILE   128
#define NHT     (HH/HTILE)     // 16 h-tiles per chunk

typedef __fp16 half2v __attribute__((ext_vector_type(2)));

// ---------------------------------------------------------------------------
// Phase 3: fp32 NT GEMM  C[m,n] = sum_k A[m,k]*B[n,k] + bias[n]
// 128x128 tile, 256 threads, 8x8 per thread, BK=8. (unchanged)
// ---------------------------------------------------------------------------
__global__ __launch_bounds__(256) void gemm_nt_bias(
    const float* __restrict__ A, const float* __restrict__ B,
    const float* __restrict__ bias, float* __restrict__ C,
    int M, int N, int K)
{
    __shared__ float As[8][128];
    __shared__ float Bs[8][128];

    const int tid = threadIdx.x;
    const int bm = blockIdx.x * 128;
    const int bn = blockIdx.y * 128;

    const int lrow = tid >> 1;
    const int lk   = (tid & 1) * 4;

    const int ty = tid >> 4;
    const int tx = tid & 15;

    float acc[8][8];
#pragma unroll
    for (int i = 0; i < 8; i++)
#pragma unroll
        for (int j = 0; j < 8; j++) acc[i][j] = 0.f;

    for (int k0 = 0; k0 < K; k0 += 8) {
        float4 av = *(const float4*)&A[(size_t)(bm + lrow) * K + k0 + lk];
        float4 bv = *(const float4*)&B[(size_t)(bn + lrow) * K + k0 + lk];
        __syncthreads();
        As[lk + 0][lrow] = av.x; As[lk + 1][lrow] = av.y;
        As[lk + 2][lrow] = av.z; As[lk + 3][lrow] = av.w;
        Bs[lk + 0][lrow] = bv.x; Bs[lk + 1][lrow] = bv.y;
        Bs[lk + 2][lrow] = bv.z; Bs[lk + 3][lrow] = bv.w;
        __syncthreads();
#pragma unroll
        for (int kk = 0; kk < 8; kk++) {
            float a[8], b[8];
            *(float4*)&a[0] = *(const float4*)&As[kk][ty * 4];
            *(float4*)&a[4] = *(const float4*)&As[kk][64 + ty * 4];
            *(float4*)&b[0] = *(const float4*)&Bs[kk][tx * 4];
            *(float4*)&b[4] = *(const float4*)&Bs[kk][64 + tx * 4];
#pragma unroll
            for (int i = 0; i < 8; i++)
#pragma unroll
                for (int j = 0; j < 8; j++)
                    acc[i][j] += a[i] * b[j];
        }
    }

#pragma unroll
    for (int g = 0; g < 2; g++) {
        const int n = bn + g * 64 + tx * 4;
        float4 bv = *(const float4*)&bias[n];
#pragma unroll
        for (int i = 0; i < 8; i++) {
            const int m = bm + ((i < 4) ? (ty * 4 + i) : (64 + ty * 4 + (i - 4)));
            float4 cv;
            cv.x = acc[i][g * 4 + 0] + bv.x;
            cv.y = acc[i][g * 4 + 1] + bv.y;
            cv.z = acc[i][g * 4 + 2] + bv.z;
            cv.w = acc[i][g * 4 + 3] + bv.w;
            *(float4*)&C[(size_t)m * N + n] = cv;
        }
    }
}

// ---------------------------------------------------------------------------
// R10 FUSED kernel: 256 blocks x 1024 threads, exactly 1 block/CU
// (breadth-first dispatch verified via OccupancyPercent in R6/R7).
//   blocks 0..127   : R9 scan (unchanged except xp chunk-gating)
//   blocks 128..255 : phase-1 xp GEMM workers (t-major tiles), so the
//                     34-GFLOP input projection overlaps the scan instead
//                     of serializing before it (~0.57 ms -> ~0.06 ms stall).
// Handshake: workers store xp with agent-scope stores, then one thread
// release-adds chunk_done[chunk] after __syncthreads (all stores at
// coherence point). Scan writer lanes poll chunk_done[t>>6]==NHT only when
// the chunk index changes (every 64 steps, almost always already armed).
// Workers never wait on the scan -> no deadlock possible.
// ---------------------------------------------------------------------------
__global__ __launch_bounds__(1024) void rnn_fused(
    const float* __restrict__ x,     // (T,H) input
    const float* __restrict__ Wih,   // (H,H)
    const float* __restrict__ bih,   // (H)
    const float* __restrict__ Whh,   // (H,H)
    const float* __restrict__ bhh,   // (H)
    const float* __restrict__ h0,    // (H)
    float* __restrict__ xp,          // (T,H) workspace: input projection
    float* __restrict__ outs,        // (T,H) hidden states out
    unsigned long long* __restrict__ mbox,  // [2][MBW] tagged fp16x2 mailbox
    int* __restrict__ chunk_done)    // [NCHUNK] xp-chunk arm counters
{
    const int tid = threadIdx.x;     // 0..1023

    if (blockIdx.x >= NB) {
        // ------------------- xp GEMM worker -------------------
        __shared__ float As[16][65];     // [kk][t-row], padded
        __shared__ float Bs[16][132];    // [kk][h-col], padded+aligned

        const int w2   = blockIdx.x - NB;   // 0..127
        const int ty   = tid >> 5;          // 0..31 -> t-rows ty*2, ty*2+1
        const int tx   = tid & 31;          // 0..31 -> h-cols tx*4..
        const int arow = tid >> 4;          // 0..63
        const int akk  = tid & 15;
        const int bcol = tid >> 3;          // 0..127
        const int bkk  = (tid & 7) * 2;

        for (int round = 0; round < (NCHUNK * NHT) / 128; ++round) {
            const int tile  = w2 + 128 * round;   // t-major: early t first
            const int chunk = tile >> 4;
            const int htile = tile & 15;
            const int bm = chunk * CHUNK_T;
            const int bn = htile * HTILE;

            float acc[2][4];
#pragma unroll
            for (int i = 0; i < 2; ++i)
#pragma unroll
                for (int j = 0; j < 4; ++j) acc[i][j] = 0.f;

            for (int k0 = 0; k0 < HH; k0 += 16) {
                float  av = x[(size_t)(bm + arow) * HH + k0 + akk];
                float2 bv = *(const float2*)&Wih[(size_t)(bn + bcol) * HH + k0 + bkk];
                __syncthreads();
                As[akk][arow]     = av;
                Bs[bkk][bcol]     = bv.x;
                Bs[bkk + 1][bcol] = bv.y;
                __syncthreads();
#pragma unroll
                for (int kk = 0; kk < 16; ++kk) {
                    float a0 = As[kk][ty * 2];
                    float a1 = As[kk][ty * 2 + 1];
                    float b0 = Bs[kk][tx * 4 + 0];
                    float b1 = Bs[kk][tx * 4 + 1];
                    float b2 = Bs[kk][tx * 4 + 2];
                    float b3 = Bs[kk][tx * 4 + 3];
                    acc[0][0] += a0 * b0; acc[0][1] += a0 * b1;
                    acc[0][2] += a0 * b2; acc[0][3] += a0 * b3;
                    acc[1][0] += a1 * b0; acc[1][1] += a1 * b1;
                    acc[1][2] += a1 * b2; acc[1][3] += a1 * b3;
                }
            }
            // epilogue: bias + agent-scope stores (visible at L3 for scan)
#pragma unroll
            for (int i = 0; i < 2; ++i) {
                const int m = bm + ty * 2 + i;
#pragma unroll
                for (int j = 0; j < 4; ++j) {
                    const int n = bn + tx * 4 + j;
                    __hip_atomic_store(&xp[(size_t)m * HH + n],
                                       acc[i][j] + bih[n],
                                       __ATOMIC_RELAXED, __HIP_MEMORY_SCOPE_AGENT);
                }
            }
            __syncthreads();   // all waves' stores retired (vmcnt0) first
            if (tid == 0)
                __hip_atomic_fetch_add(&chunk_done[chunk], 1,
                                       __ATOMIC_RELEASE, __HIP_MEMORY_SCOPE_AGENT);
        }
        return;
    }

    // ------------------------- scan (R9, unchanged core) -------------------
    const int b    = blockIdx.x;     // 0..127
    const int wave = tid >> 6;       // 0..15
    const int lane = tid & 63;
    const int r    = lane & 15;      // local row 0..15
    const int q    = lane >> 4;      // 0..3: interleaved 4-float subchunk
    const int row  = b * RPB + r;    // global row this thread accumulates
    const int m0   = wave * 64 + lane;      // my mailbox word (covers 2 rows)
    const int s0   = wave * 128 + 2 * lane; // my 2 floats in hs

    // weights pinned (atomic loads can't be rematerialized into the loop)
    float w[32];
#pragma unroll
    for (int jj = 0; jj < 8; ++jj)
#pragma unroll
        for (int i = 0; i < 4; ++i)
            w[jj * 4 + i] = __hip_atomic_load(
                &Whh[(size_t)row * HH + wave * 128 + jj * 16 + q * 4 + i],
                __ATOMIC_RELAXED, __HIP_MEMORY_SCOPE_WORKGROUP);

    const bool is_writer = (wave == 0) && (lane < RPB);
    const float bias = is_writer ? bhh[b * RPB + lane] : 0.f;

    __shared__ float hs[HH];               // staged h (fp32), wave-private
    __shared__ float partial[16][68];      // [k-chunk wave][q*17 + r]

    int last_c = -1;

    for (int t = 0; t < TT; ++t) {
        // xp gating + load: only writer lanes; poll only at chunk boundary
        float xpv = 0.f;
        if (is_writer) {
            const int c = t >> 6;   // t / CHUNK_T
            if (c != last_c) {
                while (__hip_atomic_load(&chunk_done[c],
                        __ATOMIC_RELAXED, __HIP_MEMORY_SCOPE_AGENT) < NHT) {}
                last_c = c;
            }
            xpv = __hip_atomic_load(&xp[(size_t)t * HH + b * RPB + lane],
                                    __ATOMIC_RELAXED, __HIP_MEMORY_SCOPE_AGENT);
        }

        // stage MY wave's 128-float chunk: ONE tagged word per lane
        if (t == 0) {
            float2 hv; hv.x = h0[s0]; hv.y = h0[s0 + 1];
            *(float2*)&hs[s0] = hv;
        } else {
            const unsigned int want = (unsigned int)t;
            const unsigned long long* mb = mbox + (size_t)(t & 1) * MBW;
            unsigned long long v;
            do {
                v = __hip_atomic_load(&mb[m0],
                    __ATOMIC_RELAXED, __HIP_MEMORY_SCOPE_AGENT);
            } while ((unsigned int)(v >> 32) != want);
            half2v hp = __builtin_bit_cast(half2v, (unsigned int)v);
            float2 hv;
            hv.x = (float)hp[0];
            hv.y = (float)hp[1];
            *(float2*)&hs[s0] = hv;   // same-wave write->read: lgkmcnt only
        }

        // matvec partial: 8 broadcast ds_read_b128 + 32 FMA (interleaved map)
        const float* hk = &hs[wave * 128 + q * 4];
        float p = 0.f;
#pragma unroll
        for (int jj = 0; jj < 8; ++jj) {
            float4 h4 = *(const float4*)&hk[jj * 16];
            p += w[jj * 4 + 0] * h4.x + w[jj * 4 + 1] * h4.y
               + w[jj * 4 + 2] * h4.z + w[jj * 4 + 3] * h4.w;
        }
        partial[wave][q * 17 + r] = p;
        __syncthreads();   // (B) the ONLY barrier per step

        if (wave == 0) {
            // lane l: row = l&15, qq = l>>4; sum over the 16 k-chunk waves
            const int idx = (lane >> 4) * 17 + (lane & 15);
            float s = 0.f;
#pragma unroll
            for (int g = 0; g < 16; ++g) s += partial[g][idx];
            s += __shfl_xor(s, 16, 64);   // fold qq bit 0
            s += __shfl_xor(s, 32, 64);   // fold qq bit 1
            float z = xpv + bias + s;
            z = fminf(15.f, fmaxf(-15.f, z));
            float e = __builtin_exp2f(z * 2.885390082f);
            float hv = (e - 1.f) * __builtin_amdgcn_rcpf(e + 1.f);
            // pack rows 2i,2i+1 into lane i (i<8): one 64B-line publish
            float ha = __shfl(hv, 2 * lane, 64);
            float hb = __shfl(hv, 2 * lane + 1, 64);
            if (lane < 8) {
                half2v pk2 = __builtin_amdgcn_cvt_pkrtz(ha, hb);
                unsigned int pb = __builtin_bit_cast(unsigned int, pk2);
                unsigned long long word =
                    ((unsigned long long)(unsigned int)(t + 1) << 32) |
                    (unsigned long long)pb;
                __hip_atomic_store(&mbox[(size_t)((t + 1) & 1) * MBW + b * 8 + lane],
                                   word, __ATOMIC_RELAXED, __HIP_MEMORY_SCOPE_AGENT);
            }
            if (lane < RPB)
                outs[(size_t)t * HH + b * RPB + lane] = hv;  // exact fp32
        }
        // no other barrier: partial[w] overwrite for t+1 is gated by wave w's
        // t+1 poll, which requires this block's wave-0 publish (after reads).
    }
}

// ---------------------------------------------------------------------------
extern "C" void kernel_launch(void* const* d_in, const int* in_sizes, int n_in,
                              void* d_out, int out_size, void* d_ws, size_t ws_size,
                              hipStream_t stream)
{
    const float* x     = (const float*)d_in[0];  // (T,1,H)
    const float* W_ih  = (const float*)d_in[1];  // (H,H)
    const float* W_hh  = (const float*)d_in[2];  // (H,H)
    const float* b_ih  = (const float*)d_in[3];  // (H)
    const float* b_hh  = (const float*)d_in[4];  // (H)
    const float* W_lin = (const float*)d_in[5];  // (O,H)
    const float* b_lin = (const float*)d_in[6];  // (O)
    const float* h0    = (const float*)d_in[7];  // (1,1,H)
    float* out = (float*)d_out;                  // (T,1,O)

    char* ws = (char*)d_ws;
    float* xp    = (float*)ws;                                       // 32 MB
    float* outs  = (float*)(ws + (size_t)TT * HH * 4);               // 32 MB
    unsigned long long* mbox =
        (unsigned long long*)(ws + 2 * (size_t)TT * HH * 4);         // 16 KB
    int* chunk_done =
        (int*)(ws + 2 * (size_t)TT * HH * 4 + 2 * MBW * 8);          // 256 B

    // chunk counters must start at 0 (ws arrives poisoned); mailbox needs
    // no init (t==0 reads h0; poisoned tag never equals a wanted tag).
    hipMemsetAsync(chunk_done, 0, NCHUNK * sizeof(int), stream);

    // Fused phase 1 + phase 2: scan blocks 0..127, xp workers 128..255
    rnn_fused<<<2 * NB, 1024, 0, stream>>>(
        x, W_ih, b_ih, W_hh, b_hh, h0, xp, outs, mbox, chunk_done);

    // Phase 3: out = outs @ W_lin^T + b_lin (dispatch-boundary coherence)
    gemm_nt_bias<<<dim3(TT / 128, OO / 128), 256, 0, stream>>>(
        outs, W_lin, b_lin, out, TT, OO, HH);
}